// Round 2
// baseline (1387.176 us; speedup 1.0000x reference)
//
#include <hip/hip_runtime.h>

#define HWS   65536   // 256*256
#define NCH   192     // 3*C
#define CDIM  64
#define SROWS 66              // 64 output rows + 2 halo
#define SPOS  (SROWS * 256)   // 16896 positions in a qkv strip
#define OPOS  (64 * 256)      // 16384 output positions per strip

// ---------------- zero small accumulators ----------------
__global__ void k_zero(float* __restrict__ p, int n) {
    int i = blockIdx.x * 256 + threadIdx.x;
    if (i < n) p[i] = 0.f;
}

// ---------------- Kernel A: qkv 1x1 complex conv, one 66-row strip ----------------
// x_b: [64][HWS][2]; qs: [192][SPOS][2]; strip s covers w in [s*64-1, s*64+64]
__global__ __launch_bounds__(256) void k_qkv_strip(const float* __restrict__ x,
                                                   const float* __restrict__ wr,
                                                   const float* __restrict__ wi,
                                                   float* __restrict__ qs,
                                                   int s) {
    __shared__ float2 xs[64][64];   // [ci][p]   32 KB
    __shared__ float2 wsh[192][16]; // [co][cic] 24 KB
    const int p0   = blockIdx.x << 6;   // 64 positions, all in one strip row
    const int lane = threadIdx.x & 63;
    const int grp  = threadIdx.x >> 6;  // 0..3 -> 48 co each

    const int r  = p0 >> 8;             // strip row 0..65
    const int h0 = p0 & 255;
    const int w  = s * 64 - 1 + r;      // image row, may be out of range
    const bool valid = (unsigned)w < 256u;

    const float2* x2 = (const float2*)x;
    for (int i = threadIdx.x; i < 64 * 64; i += 256) {
        int ci = i >> 6, pp = i & 63;
        xs[ci][pp] = valid ? x2[(size_t)ci * HWS + w * 256 + h0 + pp]
                           : make_float2(0.f, 0.f);
    }

    float accr[48], acci[48];
#pragma unroll
    for (int j = 0; j < 48; ++j) { accr[j] = 0.f; acci[j] = 0.f; }

    for (int cc = 0; cc < 4; ++cc) {
        __syncthreads();
        for (int i = threadIdx.x; i < 192 * 16; i += 256) {
            int co = i >> 4, cic = i & 15;
            wsh[co][cic] = make_float2(wr[co * 64 + cc * 16 + cic],
                                       wi[co * 64 + cc * 16 + cic]);
        }
        __syncthreads();
        for (int cic = 0; cic < 16; ++cic) {
            float2 xv = xs[cc * 16 + cic][lane];
#pragma unroll
            for (int j = 0; j < 48; ++j) {
                float2 wv = wsh[grp * 48 + j][cic];
                accr[j] = fmaf(wv.x, xv.x, accr[j]);
                accr[j] = fmaf(-wv.y, xv.y, accr[j]);
                acci[j] = fmaf(wv.y, xv.x, acci[j]);
                acci[j] = fmaf(wv.x, xv.y, acci[j]);
            }
        }
    }

    float2* o2 = (float2*)qs + p0 + lane;
#pragma unroll
    for (int j = 0; j < 48; ++j)
        o2[(size_t)(grp * 48 + j) * SPOS] = make_float2(accr[j], acci[j]);
}

// ---------------- Kernel B: depthwise 3x3 complex conv on a strip ----------------
// qs: [192][SPOS][2]; q,k (ch<128) -> dwqk [128][OPOS][2]; v (ch>=128) -> vout [64][HWS][2]
__global__ __launch_bounds__(256) void k_dw_strip(const float* __restrict__ qs,
                                                  const float* __restrict__ wr,
                                                  const float* __restrict__ wi,
                                                  float* __restrict__ dwqk,
                                                  float* __restrict__ vout,
                                                  int s) {
    int gid = blockIdx.x * 256 + threadIdx.x;   // over 192*OPOS
    int p   = gid & (OPOS - 1);
    int ch  = gid >> 14;
    int r64 = p >> 8, h = p & 255;
    const float2* src = (const float2*)qs + (size_t)ch * SPOS;

    float wrl[9], wil[9];
#pragma unroll
    for (int t = 0; t < 9; ++t) { wrl[t] = wr[ch * 9 + t]; wil[t] = wi[ch * 9 + t]; }

    float ar = 0.f, ai = 0.f;
#pragma unroll
    for (int du = -1; du <= 1; ++du) {
        int rin = r64 + 1 + du;   // 0..65, always in strip (w-halo pre-zeroed)
#pragma unroll
        for (int dv = -1; dv <= 1; ++dv) {
            int hh = h + dv;
            if ((unsigned)hh >= 256u) continue;
            float2 v = src[rin * 256 + hh];
            float wr_ = wrl[(du + 1) * 3 + dv + 1];
            float wi_ = wil[(du + 1) * 3 + dv + 1];
            ar = fmaf(wr_, v.x, ar); ar = fmaf(-wi_, v.y, ar);
            ai = fmaf(wi_, v.x, ai); ai = fmaf(wr_, v.y, ai);
        }
    }
    if (ch < 128)
        ((float2*)dwqk)[(size_t)ch * OPOS + p] = make_float2(ar, ai);
    else
        ((float2*)vout)[(size_t)(ch - 128) * HWS + (s * 64 + r64) * 256 + h] =
            make_float2(ar, ai);
}

// ---------------- Kernel C: fused sumsq + q k^T over one strip (atomic accumulate) ----------------
// dwqk: [128][OPOS][2] (q=0..63, k=64..127); rnsum: [2][128][2]; attn: [2][2][64][64]
__global__ __launch_bounds__(256) void k_qk_sums(const float* __restrict__ dwqk,
                                                 float* __restrict__ rnsum,
                                                 float* __restrict__ attn,
                                                 int b) {
    const int p0 = blockIdx.x << 7;          // 128 positions per block
    const int tx = threadIdx.x & 15, ty = threadIdx.x >> 4;

    __shared__ float2 qsm[64][33];
    __shared__ float2 ksm[64][33];

    float acc[2][4][4];
#pragma unroll
    for (int d = 0; d < 2; ++d)
#pragma unroll
        for (int i = 0; i < 4; ++i)
#pragma unroll
            for (int j = 0; j < 4; ++j) acc[d][i][j] = 0.f;
    float ssum = 0.f;

    const int sel = threadIdx.x >> 7;        // 0=q, 1=k  (for sumsq phase)
    const int sch = (threadIdx.x & 127) >> 1;
    const int sd  = threadIdx.x & 1;
    const float2* d2 = (const float2*)dwqk;

    for (int sc = 0; sc < 128; sc += 32) {
        __syncthreads();
        for (int i = threadIdx.x; i < 4096; i += 256) {
            int gsel = i >> 11, c = (i >> 5) & 63, ss = i & 31;
            float2 v = d2[(size_t)(gsel * 64 + c) * OPOS + p0 + sc + ss];
            if (gsel) ksm[c][ss] = v; else qsm[c][ss] = v;
        }
        __syncthreads();
        // sumsq partials
        for (int ss = 0; ss < 32; ++ss) {
            float2 v = sel ? ksm[sch][ss] : qsm[sch][ss];
            float t = sd ? v.y : v.x;
            ssum = fmaf(t, t, ssum);
        }
        // q k^T partials
        for (int ss = 0; ss < 32; ++ss) {
            float2 qv[4], kv[4];
#pragma unroll
            for (int i = 0; i < 4; ++i) {
                qv[i] = qsm[ty + 16 * i][ss];
                kv[i] = ksm[tx + 16 * i][ss];
            }
#pragma unroll
            for (int i = 0; i < 4; ++i)
#pragma unroll
                for (int j = 0; j < 4; ++j) {
                    acc[0][i][j] = fmaf(qv[i].x, kv[j].x, acc[0][i][j]);
                    acc[1][i][j] = fmaf(qv[i].y, kv[j].y, acc[1][i][j]);
                }
        }
    }

    atomicAdd(&rnsum[(b * 128 + sel * 64 + sch) * 2 + sd], ssum);
#pragma unroll
    for (int d = 0; d < 2; ++d)
#pragma unroll
        for (int i = 0; i < 4; ++i)
#pragma unroll
            for (int j = 0; j < 4; ++j)
                atomicAdd(&attn[((b * 2 + d) * 64 + ty + 16 * i) * 64 + tx + 16 * j],
                          acc[d][i][j]);
}

// ---------------- Kernel D: scale + softmax + build M1..M4 ----------------
// attn: [2][2][64][64]; rnsum: [2][128][2]; Mint: [2][64][64][4]
__global__ __launch_bounds__(256) void k_soft(const float* __restrict__ attn,
                                              const float* __restrict__ rnsum,
                                              const float* __restrict__ pwr,
                                              const float* __restrict__ pwi,
                                              float* __restrict__ Mint) {
    int b = blockIdx.x;
    __shared__ float A[2][64][64];
    __shared__ float rq[2][64], rk[2][64];
    if (threadIdx.x < 256) {
        int ch = threadIdx.x & 127, d = threadIdx.x >> 7;
        float s = rnsum[(b * 128 + ch) * 2 + d];
        float r = 1.0f / fmaxf(sqrtf(s), 1e-12f);
        if (ch < 64) rq[d][ch] = r; else rk[d][ch - 64] = r;
    }
    __syncthreads();
    for (int i = threadIdx.x; i < 2 * 64 * 64; i += 256) {
        int d = i >> 12, cq = (i >> 6) & 63, ce = i & 63;
        float v = attn[(b * 2 + d) * 4096 + cq * 64 + ce];
        A[d][cq][ce] = v * rq[d][cq] * rk[d][ce];
    }
    __syncthreads();
    if (threadIdx.x < 128) {
        int d = threadIdx.x >> 6, cq = threadIdx.x & 63;
        float m = -1e30f;
        for (int e = 0; e < 64; ++e) m = fmaxf(m, A[d][cq][e]);
        float s = 0.f;
        for (int e = 0; e < 64; ++e) { float ev = __expf(A[d][cq][e] - m); A[d][cq][e] = ev; s += ev; }
        float r = 1.0f / s;
        for (int e = 0; e < 64; ++e) A[d][cq][e] *= r;
    }
    __syncthreads();
    // M1 = Pr*A0, M2 = Pi*A1, M3 = Pr*A1, M4 = Pi*A0
    for (int i = threadIdx.x; i < 4096; i += 256) {
        int co = i >> 6, e = i & 63;
        float m1 = 0.f, m2 = 0.f, m3 = 0.f, m4 = 0.f;
        for (int c = 0; c < 64; ++c) {
            float pr = pwr[co * 64 + c], pi = pwi[co * 64 + c];
            float a0 = A[0][c][e], a1 = A[1][c][e];
            m1 = fmaf(pr, a0, m1);
            m2 = fmaf(pi, a1, m2);
            m3 = fmaf(pr, a1, m3);
            m4 = fmaf(pi, a0, m4);
        }
        ((float4*)Mint)[(size_t)b * 4096 + i] = make_float4(m1, m2, m3, m4);
    }
}

// ---------------- Kernel E: out = proj(attn*v), in-place on d_out ----------------
// out holds v ([b][64][HWS][2]) on entry; overwritten with final output.
__global__ __launch_bounds__(256) void k_out(const float* __restrict__ Mint,
                                             float* __restrict__ out) {
    int b = blockIdx.x >> 10;
    int p0 = (blockIdx.x & 1023) << 6;
    int lane = threadIdx.x & 63, grp = threadIdx.x >> 6;
    __shared__ float2 vs[64][64];
    float2* base = (float2*)out + (size_t)b * 64 * HWS;
    for (int i = threadIdx.x; i < 4096; i += 256) {
        int e = i >> 6, pp = i & 63;
        vs[e][pp] = base[(size_t)e * HWS + p0 + pp];
    }
    __syncthreads();
    const float4* M = (const float4*)Mint + (size_t)b * 4096;
    float2* o2 = base + p0 + lane;
    for (int j = 0; j < 16; ++j) {
        int co = grp * 16 + j;
        float ar = 0.f, ai = 0.f;
#pragma unroll 8
        for (int e = 0; e < 64; ++e) {
            float4 m = M[co * 64 + e];
            float2 v = vs[e][lane];
            ar = fmaf(m.x, v.x, ar); ar = fmaf(-m.y, v.y, ar);
            ai = fmaf(m.z, v.y, ai); ai = fmaf(m.w, v.x, ai);
        }
        o2[(size_t)co * HWS] = make_float2(ar, ai);
    }
}

extern "C" void kernel_launch(void* const* d_in, const int* in_sizes, int n_in,
                              void* d_out, int out_size, void* d_ws, size_t ws_size,
                              hipStream_t stream) {
    const float* x      = (const float*)d_in[0];
    const float* qkv_wr = (const float*)d_in[1];
    const float* qkv_wi = (const float*)d_in[2];
    const float* dw_wr  = (const float*)d_in[3];
    const float* dw_wi  = (const float*)d_in[4];
    const float* p_wr   = (const float*)d_in[5];
    const float* p_wi   = (const float*)d_in[6];
    float* out = (float*)d_out;

    float* wsf   = (float*)d_ws;
    float* dwqk  = wsf;                       // 128*OPOS*2 = 4,194,304 f (16.8 MB)
    float* qs    = dwqk + (size_t)128 * OPOS * 2;  // 192*SPOS*2 = 6,488,064 f (26 MB)
    float* rnsum = qs + (size_t)NCH * SPOS * 2;    // 512 f
    float* attn  = rnsum + 512;               // 16384 f
    float* Mint  = attn + 16384;              // 32768 f
    // total ~43 MB

    k_zero<<<66, 256, 0, stream>>>(rnsum, 512 + 16384);

    for (int b = 0; b < 2; ++b) {
        const float* xb = x + (size_t)b * CDIM * HWS * 2;
        float* vout = out + (size_t)b * CDIM * HWS * 2;
        for (int s = 0; s < 4; ++s) {
            k_qkv_strip<<<SPOS / 64, 256, 0, stream>>>(xb, qkv_wr, qkv_wi, qs, s);
            k_dw_strip<<<NCH * OPOS / 256, 256, 0, stream>>>(qs, dw_wr, dw_wi,
                                                             dwqk, vout, s);
            k_qk_sums<<<OPOS / 128, 256, 0, stream>>>(dwqk, rnsum, attn, b);
        }
    }
    k_soft<<<2, 256, 0, stream>>>(attn, rnsum, p_wr, p_wi, Mint);
    k_out<<<2048, 256, 0, stream>>>(Mint, out);
}

// Round 3
// 576.363 us; speedup vs baseline: 2.4068x; 2.4068x over previous
//
#include <hip/hip_runtime.h>

#define HWS 65536   // 256*256

typedef __attribute__((ext_vector_type(8))) short bf16x8;
typedef __attribute__((ext_vector_type(4))) float f32x4;
typedef unsigned int u32;
typedef unsigned short u16;

__device__ __forceinline__ u16 f2bf(float x) {
    u32 u = __float_as_uint(x);
    return (u16)((u + 0x7fffu + ((u >> 16) & 1u)) >> 16);
}
__device__ __forceinline__ float bf2f(u32 h) { return __uint_as_float(h << 16); }
__device__ __forceinline__ u32 pack2(float r, float i) {
    return (u32)f2bf(r) | ((u32)f2bf(i) << 16);
}

// ---------------- tiny helpers ----------------
__global__ void k_zero(float* __restrict__ p, int n) {
    int i = blockIdx.x * 256 + threadIdx.x;
    if (i < n) p[i] = 0.f;
}

// convert qkv weights to bf16 planes: [Wr | Wi | -Wi], each [192][64]
__global__ void k_wcvt(const float* __restrict__ wr, const float* __restrict__ wi,
                       u16* __restrict__ wbf) {
    int i = blockIdx.x * 256 + threadIdx.x;
    if (i < 12288) {
        wbf[i]         = f2bf(wr[i]);
        wbf[12288 + i] = f2bf(wi[i]);
        wbf[24576 + i] = f2bf(-wi[i]);
    }
}

// ---------------- Kernel A: qkv 1x1 complex conv via bf16 MFMA ----------------
// x_b: [64][HWS][2] f32; qs: [192][(R+2)*256] packed bf16 (r,i); strip s covers w in [s*R-1, s*R+R]
__global__ __launch_bounds__(256) void k_qkv(const float* __restrict__ x,
                                             const u16* __restrict__ wbf,
                                             u32* __restrict__ qs,
                                             int s, int R) {
    __shared__ u16 Wr[64][72], Wi[64][72], Wn[64][72];  // [co][ci], pad 72
    __shared__ u16 Xr[64][72], Xi[64][72];              // [p][ci],  pad 72
    const int ptile = blockIdx.x, cog = blockIdx.y;     // cog: 0..2 -> 64 co each
    const int row = ptile >> 2, h0 = (ptile & 3) << 6;  // strip row, h offset
    const int w = s * R - 1 + row;                      // image row (may be OOB)
    const bool valid = (unsigned)w < 256u;
    const int SPz = (R + 2) << 8;
    const int t = threadIdx.x;

    for (int i = t; i < 4096; i += 256) {
        int co = i >> 6, ci = i & 63;
        int g = (cog * 64 + co) * 64 + ci;
        Wr[co][ci] = wbf[g];
        Wi[co][ci] = wbf[12288 + g];
        Wn[co][ci] = wbf[24576 + g];
    }
    const float2* x2 = (const float2*)x;
    for (int i = t; i < 4096; i += 256) {
        int ci = i >> 6, pp = i & 63;
        float2 v = valid ? x2[(size_t)ci * HWS + w * 256 + h0 + pp]
                         : make_float2(0.f, 0.f);
        Xr[pp][ci] = f2bf(v.x);
        Xi[pp][ci] = f2bf(v.y);
    }
    __syncthreads();

    const int lane = t & 63, wid = t >> 6;
    const int wy = wid >> 1, wx = wid & 1;     // wave tile: co-half, p-half
    const int l15 = lane & 15, l4 = lane >> 4;

    bf16x8 Afr[2][2], Afi[2][2], Afn[2][2], Bfr[2][2], Bfi[2][2];
#pragma unroll
    for (int cf = 0; cf < 2; ++cf)
#pragma unroll
        for (int ks = 0; ks < 2; ++ks) {
            int r0 = 32 * wy + 16 * cf + l15, c0 = 32 * ks + 8 * l4;
            Afr[cf][ks] = *(const bf16x8*)&Wr[r0][c0];
            Afi[cf][ks] = *(const bf16x8*)&Wi[r0][c0];
            Afn[cf][ks] = *(const bf16x8*)&Wn[r0][c0];
        }
#pragma unroll
    for (int pf = 0; pf < 2; ++pf)
#pragma unroll
        for (int ks = 0; ks < 2; ++ks) {
            int r0 = 32 * wx + 16 * pf + l15, c0 = 32 * ks + 8 * l4;
            Bfr[pf][ks] = *(const bf16x8*)&Xr[r0][c0];
            Bfi[pf][ks] = *(const bf16x8*)&Xi[r0][c0];
        }

    f32x4 zz = {0.f, 0.f, 0.f, 0.f};
    f32x4 accr[2][2], acci[2][2];
#pragma unroll
    for (int cf = 0; cf < 2; ++cf)
#pragma unroll
        for (int pf = 0; pf < 2; ++pf) { accr[cf][pf] = zz; acci[cf][pf] = zz; }

#pragma unroll
    for (int ks = 0; ks < 2; ++ks)
#pragma unroll
        for (int cf = 0; cf < 2; ++cf)
#pragma unroll
            for (int pf = 0; pf < 2; ++pf) {
                accr[cf][pf] = __builtin_amdgcn_mfma_f32_16x16x32_bf16(Afr[cf][ks], Bfr[pf][ks], accr[cf][pf], 0, 0, 0);
                accr[cf][pf] = __builtin_amdgcn_mfma_f32_16x16x32_bf16(Afn[cf][ks], Bfi[pf][ks], accr[cf][pf], 0, 0, 0);
                acci[cf][pf] = __builtin_amdgcn_mfma_f32_16x16x32_bf16(Afi[cf][ks], Bfr[pf][ks], acci[cf][pf], 0, 0, 0);
                acci[cf][pf] = __builtin_amdgcn_mfma_f32_16x16x32_bf16(Afr[cf][ks], Bfi[pf][ks], acci[cf][pf], 0, 0, 0);
            }

#pragma unroll
    for (int cf = 0; cf < 2; ++cf)
#pragma unroll
        for (int pf = 0; pf < 2; ++pf)
#pragma unroll
            for (int r = 0; r < 4; ++r) {
                int co = cog * 64 + 32 * wy + 16 * cf + 4 * l4 + r;
                int p  = row * 256 + h0 + 32 * wx + 16 * pf + l15;
                qs[(size_t)co * SPz + p] = pack2(accr[cf][pf][r], acci[cf][pf][r]);
            }
}

// ---------------- Kernel B: depthwise 3x3 complex conv on a strip ----------------
// qs: packed bf16 [192][(R+2)*256]; ch<128 -> dwqk packed bf16 [128][R*256]; ch>=128 -> vout f32 [64][HWS][2]
__global__ __launch_bounds__(256) void k_dw(const u32* __restrict__ qs,
                                            const float* __restrict__ wr,
                                            const float* __restrict__ wi,
                                            u32* __restrict__ dwqk,
                                            float* __restrict__ vout,
                                            int s, int R, int ls) {
    int gid = blockIdx.x * 256 + threadIdx.x;   // over 192*R*256
    int SP = R << 8;
    int p = gid & (SP - 1), ch = gid >> ls;
    int r64 = p >> 8, h = p & 255;
    int SPz = (R + 2) << 8;
    const u32* src = qs + (size_t)ch * SPz;

    float wrl[9], wil[9];
#pragma unroll
    for (int tt = 0; tt < 9; ++tt) { wrl[tt] = wr[ch * 9 + tt]; wil[tt] = wi[ch * 9 + tt]; }

    float ar = 0.f, ai = 0.f;
#pragma unroll
    for (int du = -1; du <= 1; ++du) {
        int rin = r64 + 1 + du;   // 0..R+1, always in strip (w-halo pre-zeroed)
#pragma unroll
        for (int dv = -1; dv <= 1; ++dv) {
            int hh = h + dv;
            if ((unsigned)hh >= 256u) continue;
            u32 u = src[rin * 256 + hh];
            float vr = bf2f(u & 0xffffu), vi = bf2f(u >> 16);
            float wr_ = wrl[(du + 1) * 3 + dv + 1];
            float wi_ = wil[(du + 1) * 3 + dv + 1];
            ar = fmaf(wr_, vr, ar); ar = fmaf(-wi_, vi, ar);
            ai = fmaf(wi_, vr, ai); ai = fmaf(wr_, vi, ai);
        }
    }
    if (ch < 128)
        dwqk[(size_t)ch * SP + p] = pack2(ar, ai);
    else
        ((float2*)vout)[(size_t)(ch - 128) * HWS + (s * R + r64) * 256 + h] =
            make_float2(ar, ai);
}

// ---------------- Kernel C: fused sumsq + q k^T over a strip (atomic accumulate) ----------------
// dwqk: packed bf16 [128][SP] (q=0..63, k=64..127); rnsum: [2][128][2]; attn: [2][2][64][64]
__global__ __launch_bounds__(256) void k_qk(const u32* __restrict__ dwqk,
                                            float* __restrict__ rnsum,
                                            float* __restrict__ attn,
                                            int b, int SP) {
    const int p0 = blockIdx.x << 7;          // 128 positions per block
    const int tx = threadIdx.x & 15, ty = threadIdx.x >> 4;

    __shared__ float2 qsm[64][33];
    __shared__ float2 ksm[64][33];

    float acc[2][4][4];
#pragma unroll
    for (int d = 0; d < 2; ++d)
#pragma unroll
        for (int i = 0; i < 4; ++i)
#pragma unroll
            for (int j = 0; j < 4; ++j) acc[d][i][j] = 0.f;
    float ssum = 0.f;

    const int sel = threadIdx.x >> 7;
    const int sch = (threadIdx.x & 127) >> 1;
    const int sd  = threadIdx.x & 1;

    for (int sc = 0; sc < 128; sc += 32) {
        __syncthreads();
        for (int i = threadIdx.x; i < 4096; i += 256) {
            int gsel = i >> 11, c = (i >> 5) & 63, ss = i & 31;
            u32 u = dwqk[(size_t)(gsel * 64 + c) * SP + p0 + sc + ss];
            float2 v = make_float2(bf2f(u & 0xffffu), bf2f(u >> 16));
            if (gsel) ksm[c][ss] = v; else qsm[c][ss] = v;
        }
        __syncthreads();
        for (int ss = 0; ss < 32; ++ss) {
            float2 v = sel ? ksm[sch][ss] : qsm[sch][ss];
            float tq = sd ? v.y : v.x;
            ssum = fmaf(tq, tq, ssum);
        }
        for (int ss = 0; ss < 32; ++ss) {
            float2 qv[4], kv[4];
#pragma unroll
            for (int i = 0; i < 4; ++i) {
                qv[i] = qsm[ty + 16 * i][ss];
                kv[i] = ksm[tx + 16 * i][ss];
            }
#pragma unroll
            for (int i = 0; i < 4; ++i)
#pragma unroll
                for (int j = 0; j < 4; ++j) {
                    acc[0][i][j] = fmaf(qv[i].x, kv[j].x, acc[0][i][j]);
                    acc[1][i][j] = fmaf(qv[i].y, kv[j].y, acc[1][i][j]);
                }
        }
    }

    atomicAdd(&rnsum[(b * 128 + sel * 64 + sch) * 2 + sd], ssum);
#pragma unroll
    for (int d = 0; d < 2; ++d)
#pragma unroll
        for (int i = 0; i < 4; ++i)
#pragma unroll
            for (int j = 0; j < 4; ++j)
                atomicAdd(&attn[((b * 2 + d) * 64 + ty + 16 * i) * 64 + tx + 16 * j],
                          acc[d][i][j]);
}

// ---------------- Kernel D: scale + softmax + build M1..M4 ----------------
__global__ __launch_bounds__(256) void k_soft(const float* __restrict__ attn,
                                              const float* __restrict__ rnsum,
                                              const float* __restrict__ pwr,
                                              const float* __restrict__ pwi,
                                              float* __restrict__ Mint) {
    int b = blockIdx.x;
    __shared__ float A[2][64][64];
    __shared__ float rq[2][64], rk[2][64];
    {
        int ch = threadIdx.x & 127, d = threadIdx.x >> 7;
        float s = rnsum[(b * 128 + ch) * 2 + d];
        float r = 1.0f / fmaxf(sqrtf(s), 1e-12f);
        if (ch < 64) rq[d][ch] = r; else rk[d][ch - 64] = r;
    }
    __syncthreads();
    for (int i = threadIdx.x; i < 2 * 64 * 64; i += 256) {
        int d = i >> 12, cq = (i >> 6) & 63, ce = i & 63;
        float v = attn[(b * 2 + d) * 4096 + cq * 64 + ce];
        A[d][cq][ce] = v * rq[d][cq] * rk[d][ce];
    }
    __syncthreads();
    if (threadIdx.x < 128) {
        int d = threadIdx.x >> 6, cq = threadIdx.x & 63;
        float m = -1e30f;
        for (int e = 0; e < 64; ++e) m = fmaxf(m, A[d][cq][e]);
        float s = 0.f;
        for (int e = 0; e < 64; ++e) { float ev = __expf(A[d][cq][e] - m); A[d][cq][e] = ev; s += ev; }
        float r = 1.0f / s;
        for (int e = 0; e < 64; ++e) A[d][cq][e] *= r;
    }
    __syncthreads();
    // M1 = Pr*A0, M2 = Pi*A1, M3 = Pr*A1, M4 = Pi*A0
    for (int i = threadIdx.x; i < 4096; i += 256) {
        int co = i >> 6, e = i & 63;
        float m1 = 0.f, m2 = 0.f, m3 = 0.f, m4 = 0.f;
        for (int c = 0; c < 64; ++c) {
            float pr = pwr[co * 64 + c], pi = pwi[co * 64 + c];
            float a0 = A[0][c][e], a1 = A[1][c][e];
            m1 = fmaf(pr, a0, m1);
            m2 = fmaf(pi, a1, m2);
            m3 = fmaf(pr, a1, m3);
            m4 = fmaf(pi, a0, m4);
        }
        ((float4*)Mint)[(size_t)b * 4096 + i] = make_float4(m1, m2, m3, m4);
    }
}

// ---------------- Kernel E: out = proj(attn*v), in-place on d_out ----------------
// out holds v ([b][64][HWS][2] f32) on entry; overwritten with final output.
__global__ __launch_bounds__(256) void k_out(const float* __restrict__ Mint,
                                             float* __restrict__ out) {
    int b  = blockIdx.x >> 9;
    int p0 = (blockIdx.x & 511) << 7;        // 128 positions per block
    int t  = threadIdx.x;
    int pg = t & 15, cg = t >> 4;            // thread: 8 pos (stride 16) x 4 co

    __shared__ float2 vs[64][128];           // 64 KB
    __shared__ float4 Ml[64][65];            // 66.6 KB, padded

    float2* base = (float2*)out + (size_t)b * 64 * HWS;
    for (int i = t; i < 8192; i += 256) {
        int e = i >> 7, pp = i & 127;
        vs[e][pp] = base[(size_t)e * HWS + p0 + pp];
    }
    const float4* M = (const float4*)Mint + (size_t)b * 4096;
    for (int i = t; i < 4096; i += 256) Ml[i >> 6][i & 63] = M[i];
    __syncthreads();

    float ar[4][8], ai[4][8];
#pragma unroll
    for (int j = 0; j < 4; ++j)
#pragma unroll
        for (int u = 0; u < 8; ++u) { ar[j][u] = 0.f; ai[j][u] = 0.f; }

    for (int e = 0; e < 64; ++e) {
        float4 mm[4];
#pragma unroll
        for (int j = 0; j < 4; ++j) mm[j] = Ml[4 * cg + j][e];
        float2 vv[8];
#pragma unroll
        for (int u = 0; u < 8; ++u) vv[u] = vs[e][pg + 16 * u];
#pragma unroll
        for (int j = 0; j < 4; ++j)
#pragma unroll
            for (int u = 0; u < 8; ++u) {
                ar[j][u] = fmaf(mm[j].x, vv[u].x, ar[j][u]);
                ar[j][u] = fmaf(-mm[j].y, vv[u].y, ar[j][u]);
                ai[j][u] = fmaf(mm[j].z, vv[u].y, ai[j][u]);
                ai[j][u] = fmaf(mm[j].w, vv[u].x, ai[j][u]);
            }
    }

#pragma unroll
    for (int j = 0; j < 4; ++j) {
        float2* o2 = base + (size_t)(4 * cg + j) * HWS + p0 + pg;
#pragma unroll
        for (int u = 0; u < 8; ++u)
            o2[16 * u] = make_float2(ar[j][u], ai[j][u]);
    }
}

extern "C" void kernel_launch(void* const* d_in, const int* in_sizes, int n_in,
                              void* d_out, int out_size, void* d_ws, size_t ws_size,
                              hipStream_t stream) {
    const float* x      = (const float*)d_in[0];
    const float* qkv_wr = (const float*)d_in[1];
    const float* qkv_wi = (const float*)d_in[2];
    const float* dw_wr  = (const float*)d_in[3];
    const float* dw_wi  = (const float*)d_in[4];
    const float* p_wr   = (const float*)d_in[5];
    const float* p_wi   = (const float*)d_in[6];
    float* out = (float*)d_out;

    // Adaptive strip height: full image if workspace allows, else 128-row strips.
    const int R  = (ws_size >= 90ull * 1000 * 1000) ? 256 : 128;
    const int S  = 256 / R;
    const int SP = R << 8;
    const int ls = (R == 256) ? 16 : 15;

    char* base = (char*)d_ws;
    size_t qs_bytes = (size_t)192 * (R + 2) * 256 * 4;
    size_t dw_bytes = (size_t)128 * SP * 4;
    u32*   qs_u   = (u32*)base;
    u32*   dwqk_u = (u32*)(base + qs_bytes);
    u16*   wbf    = (u16*)(base + qs_bytes + dw_bytes);
    float* rnsum  = (float*)(base + qs_bytes + dw_bytes + 73728);
    float* attn   = rnsum + 512;
    float* Mint   = attn + 16384;

    k_wcvt<<<48, 256, 0, stream>>>(qkv_wr, qkv_wi, wbf);
    k_zero<<<66, 256, 0, stream>>>(rnsum, 512 + 16384);

    for (int b = 0; b < 2; ++b) {
        const float* xb = x + (size_t)b * 64 * HWS * 2;
        float* vout = out + (size_t)b * 64 * HWS * 2;
        for (int s = 0; s < S; ++s) {
            k_qkv<<<dim3((R + 2) * 4, 3), 256, 0, stream>>>(xb, wbf, qs_u, s, R);
            k_dw<<<192 * R, 256, 0, stream>>>(qs_u, dw_wr, dw_wi, dwqk_u, vout, s, R, ls);
            k_qk<<<R * 2, 256, 0, stream>>>(dwqk_u, rnsum, attn, b, SP);
        }
    }
    k_soft<<<2, 256, 0, stream>>>(attn, rnsum, p_wr, p_wi, Mint);
    k_out<<<1024, 256, 0, stream>>>(Mint, out);
}

// Round 4
// 477.991 us; speedup vs baseline: 2.9021x; 1.2058x over previous
//
#include <hip/hip_runtime.h>

#define HWS 65536   // 256*256

typedef __attribute__((ext_vector_type(8))) short bf16x8;
typedef __attribute__((ext_vector_type(4))) float f32x4;
typedef unsigned int u32;
typedef unsigned short u16;

__device__ __forceinline__ u16 f2bf(float x) {
    u32 u = __float_as_uint(x);
    return (u16)((u + 0x7fffu + ((u >> 16) & 1u)) >> 16);
}
__device__ __forceinline__ float bf2f(u32 h) { return __uint_as_float(h << 16); }
__device__ __forceinline__ u32 pack2(float a, float b) {
    return (u32)f2bf(a) | ((u32)f2bf(b) << 16);
}

// ---------------- tiny helpers ----------------
__global__ void k_zero(float* __restrict__ p, int n) {
    int i = blockIdx.x * 256 + threadIdx.x;
    if (i < n) p[i] = 0.f;
}

// convert qkv weights to bf16 planes: [Wr | Wi | -Wi], each [192][64]
__global__ void k_wcvt(const float* __restrict__ wr, const float* __restrict__ wi,
                       u16* __restrict__ wbf) {
    int i = blockIdx.x * 256 + threadIdx.x;
    if (i < 12288) {
        wbf[i]         = f2bf(wr[i]);
        wbf[12288 + i] = f2bf(wi[i]);
        wbf[24576 + i] = f2bf(-wi[i]);
    }
}

// ---------------- Kernel A: qkv 1x1 complex conv via bf16 MFMA ----------------
// x_b: [64][HWS][2] f32; qs: [192][(R+2)*256] packed bf16 (r,i); strip s covers w in [s*R-1, s*R+R]
__global__ __launch_bounds__(256) void k_qkv(const float* __restrict__ x,
                                             const u16* __restrict__ wbf,
                                             u32* __restrict__ qs,
                                             int s, int R) {
    __shared__ u16 Wr[64][72], Wi[64][72], Wn[64][72];
    __shared__ u16 Xr[64][72], Xi[64][72];
    const int ptile = blockIdx.x, cog = blockIdx.y;
    const int row = ptile >> 2, h0 = (ptile & 3) << 6;
    const int w = s * R - 1 + row;
    const bool valid = (unsigned)w < 256u;
    const int SPz = (R + 2) << 8;
    const int t = threadIdx.x;

    for (int i = t; i < 4096; i += 256) {
        int co = i >> 6, ci = i & 63;
        int g = (cog * 64 + co) * 64 + ci;
        Wr[co][ci] = wbf[g];
        Wi[co][ci] = wbf[12288 + g];
        Wn[co][ci] = wbf[24576 + g];
    }
    const float2* x2 = (const float2*)x;
    for (int i = t; i < 4096; i += 256) {
        int ci = i >> 6, pp = i & 63;
        float2 v = valid ? x2[(size_t)ci * HWS + w * 256 + h0 + pp]
                         : make_float2(0.f, 0.f);
        Xr[pp][ci] = f2bf(v.x);
        Xi[pp][ci] = f2bf(v.y);
    }
    __syncthreads();

    const int lane = t & 63, wid = t >> 6;
    const int wy = wid >> 1, wx = wid & 1;
    const int l15 = lane & 15, l4 = lane >> 4;

    bf16x8 Afr[2][2], Afi[2][2], Afn[2][2], Bfr[2][2], Bfi[2][2];
#pragma unroll
    for (int cf = 0; cf < 2; ++cf)
#pragma unroll
        for (int ks = 0; ks < 2; ++ks) {
            int r0 = 32 * wy + 16 * cf + l15, c0 = 32 * ks + 8 * l4;
            Afr[cf][ks] = *(const bf16x8*)&Wr[r0][c0];
            Afi[cf][ks] = *(const bf16x8*)&Wi[r0][c0];
            Afn[cf][ks] = *(const bf16x8*)&Wn[r0][c0];
        }
#pragma unroll
    for (int pf = 0; pf < 2; ++pf)
#pragma unroll
        for (int ks = 0; ks < 2; ++ks) {
            int r0 = 32 * wx + 16 * pf + l15, c0 = 32 * ks + 8 * l4;
            Bfr[pf][ks] = *(const bf16x8*)&Xr[r0][c0];
            Bfi[pf][ks] = *(const bf16x8*)&Xi[r0][c0];
        }

    f32x4 zz = {0.f, 0.f, 0.f, 0.f};
    f32x4 accr[2][2], acci[2][2];
#pragma unroll
    for (int cf = 0; cf < 2; ++cf)
#pragma unroll
        for (int pf = 0; pf < 2; ++pf) { accr[cf][pf] = zz; acci[cf][pf] = zz; }

#pragma unroll
    for (int ks = 0; ks < 2; ++ks)
#pragma unroll
        for (int cf = 0; cf < 2; ++cf)
#pragma unroll
            for (int pf = 0; pf < 2; ++pf) {
                accr[cf][pf] = __builtin_amdgcn_mfma_f32_16x16x32_bf16(Afr[cf][ks], Bfr[pf][ks], accr[cf][pf], 0, 0, 0);
                accr[cf][pf] = __builtin_amdgcn_mfma_f32_16x16x32_bf16(Afn[cf][ks], Bfi[pf][ks], accr[cf][pf], 0, 0, 0);
                acci[cf][pf] = __builtin_amdgcn_mfma_f32_16x16x32_bf16(Afi[cf][ks], Bfr[pf][ks], acci[cf][pf], 0, 0, 0);
                acci[cf][pf] = __builtin_amdgcn_mfma_f32_16x16x32_bf16(Afr[cf][ks], Bfi[pf][ks], acci[cf][pf], 0, 0, 0);
            }

#pragma unroll
    for (int cf = 0; cf < 2; ++cf)
#pragma unroll
        for (int pf = 0; pf < 2; ++pf)
#pragma unroll
            for (int r = 0; r < 4; ++r) {
                int co = cog * 64 + 32 * wy + 16 * cf + 4 * l4 + r;
                int p  = row * 256 + h0 + 32 * wx + 16 * pf + l15;
                qs[(size_t)co * SPz + p] = pack2(accr[cf][pf][r], acci[cf][pf][r]);
            }
}

// ---------------- Kernel B: depthwise 3x3 complex conv, 2 pixels/thread ----------------
// qs packed [192][(R+2)*256]; ch<128 -> dwp planes [4][64][SP] u16 (q_r,q_i,k_r,k_i);
// ch>=128 -> vpack [64][HWS] u32 (r,i) inside d_out batch region
__global__ __launch_bounds__(256) void k_dw(const u32* __restrict__ qs,
                                            const float* __restrict__ wr,
                                            const float* __restrict__ wi,
                                            u16* __restrict__ dwp,
                                            u32* __restrict__ vpack,
                                            int s, int R, int lsh) {
    int idx = blockIdx.x * 256 + threadIdx.x;   // over 192*SP/2
    int SP = R << 8;
    int p2 = (idx & ((SP >> 1) - 1)) << 1;
    int ch = idx >> lsh;
    int r64 = p2 >> 8, h = p2 & 255;
    int SPz = (R + 2) << 8;
    const u32* src = qs + (size_t)ch * SPz + r64 * 256;

    float wrl[9], wil[9];
#pragma unroll
    for (int tt = 0; tt < 9; ++tt) { wrl[tt] = wr[ch * 9 + tt]; wil[tt] = wi[ch * 9 + tt]; }

    float a0r = 0.f, a0i = 0.f, a1r = 0.f, a1i = 0.f;
#pragma unroll
    for (int du = 0; du < 3; ++du) {
#pragma unroll
        for (int c4 = 0; c4 < 4; ++c4) {
            int hh = h - 1 + c4;
            u32 u = ((unsigned)hh < 256u) ? src[du * 256 + hh] : 0u;
            float vr = bf2f(u & 0xffffu), vi = bf2f(u >> 16);
            if (c4 < 3) {
                float w0 = wrl[du * 3 + c4], w1 = wil[du * 3 + c4];
                a0r = fmaf(w0, vr, a0r); a0r = fmaf(-w1, vi, a0r);
                a0i = fmaf(w1, vr, a0i); a0i = fmaf(w0, vi, a0i);
            }
            if (c4 > 0) {
                float w0 = wrl[du * 3 + c4 - 1], w1 = wil[du * 3 + c4 - 1];
                a1r = fmaf(w0, vr, a1r); a1r = fmaf(-w1, vi, a1r);
                a1i = fmaf(w1, vr, a1i); a1i = fmaf(w0, vi, a1i);
            }
        }
    }

    if (ch < 128) {
        int pl = (ch < 64) ? 0 : 2;
        int row = ch & 63;
        u16* base = dwp + ((size_t)pl * 64 + row) * SP + p2;
        *(u32*)base          = pack2(a0r, a1r);
        *(u32*)(base + (size_t)64 * SP) = pack2(a0i, a1i);   // imag plane (pl+1)
    } else {
        int e = ch - 128;
        uint2 vv = make_uint2(pack2(a0r, a0i), pack2(a1r, a1i));
        *(uint2*)&vpack[(size_t)e * HWS + (s * R + r64) * 256 + h] = vv;
    }
}

// ---------------- Kernel C: q k^T + fused sumsq via MFMA (no LDS) ----------------
// dwp planes [4][64][SP]; rnsum [2][128][2]; attn [2][2][64][64]
__global__ __launch_bounds__(256) void k_qk(const u16* __restrict__ dwp,
                                            float* __restrict__ rnsum,
                                            float* __restrict__ attn,
                                            int b, int SP) {
    const int chunk = blockIdx.x;        // 0..31
    const int d = blockIdx.y;
    const int Kc = SP >> 5;
    const int kc0 = chunk * Kc;
    const u16* qp = dwp + (size_t)d * 64 * SP;
    const u16* kp = dwp + (size_t)(2 + d) * 64 * SP;

    const int t = threadIdx.x, lane = t & 63, wid = t >> 6;
    const int wy = wid >> 1, wx = wid & 1;
    const int l15 = lane & 15, l4 = lane >> 4;

    f32x4 zz = {0.f, 0.f, 0.f, 0.f};
    f32x4 acc[2][2] = {{zz, zz}, {zz, zz}};
    float sq[2] = {0.f, 0.f}, sk[2] = {0.f, 0.f};

    const int iters = Kc >> 5;
    for (int ks = 0; ks < iters; ++ks) {
        int k0 = kc0 + ks * 32 + 8 * l4;
        bf16x8 aq[2], bk[2];
#pragma unroll
        for (int cf = 0; cf < 2; ++cf)
            aq[cf] = *(const bf16x8*)&qp[(size_t)(32 * wy + 16 * cf + l15) * SP + k0];
#pragma unroll
        for (int ef = 0; ef < 2; ++ef)
            bk[ef] = *(const bf16x8*)&kp[(size_t)(32 * wx + 16 * ef + l15) * SP + k0];

        if (wx == 0)
#pragma unroll
            for (int cf = 0; cf < 2; ++cf)
#pragma unroll
                for (int j = 0; j < 8; ++j) {
                    float f = bf2f((u16)aq[cf][j]);
                    sq[cf] = fmaf(f, f, sq[cf]);
                }
        if (wy == 0)
#pragma unroll
            for (int ef = 0; ef < 2; ++ef)
#pragma unroll
                for (int j = 0; j < 8; ++j) {
                    float f = bf2f((u16)bk[ef][j]);
                    sk[ef] = fmaf(f, f, sk[ef]);
                }

#pragma unroll
        for (int cf = 0; cf < 2; ++cf)
#pragma unroll
            for (int ef = 0; ef < 2; ++ef)
                acc[cf][ef] = __builtin_amdgcn_mfma_f32_16x16x32_bf16(aq[cf], bk[ef], acc[cf][ef], 0, 0, 0);
    }

#pragma unroll
    for (int cf = 0; cf < 2; ++cf)
#pragma unroll
        for (int ef = 0; ef < 2; ++ef)
#pragma unroll
            for (int r = 0; r < 4; ++r) {
                int cq = 32 * wy + 16 * cf + 4 * l4 + r;
                int ce = 32 * wx + 16 * ef + l15;
                atomicAdd(&attn[((b * 2 + d) * 64 + cq) * 64 + ce], acc[cf][ef][r]);
            }

    if (wx == 0)
#pragma unroll
        for (int cf = 0; cf < 2; ++cf) {
            float v = sq[cf];
            v += __shfl_xor(v, 16);
            v += __shfl_xor(v, 32);
            if (lane < 16)
                atomicAdd(&rnsum[((size_t)b * 128 + 32 * wy + 16 * cf + lane) * 2 + d], v);
        }
    if (wy == 0)
#pragma unroll
        for (int ef = 0; ef < 2; ++ef) {
            float v = sk[ef];
            v += __shfl_xor(v, 16);
            v += __shfl_xor(v, 32);
            if (lane < 16)
                atomicAdd(&rnsum[((size_t)b * 128 + 64 + 32 * wx + 16 * ef + lane) * 2 + d], v);
        }
}

// ---------------- Kernel D: scale + softmax + build A_big (bf16, interleaved) ----------------
// A_big[b] is [128][128] u16: row 2co+ri, col 2e+c:
//   [2co][2e]=M1 [2co][2e+1]=-M2 [2co+1][2e]=M4 [2co+1][2e+1]=M3
__global__ __launch_bounds__(256) void k_soft(const float* __restrict__ attn,
                                              const float* __restrict__ rnsum,
                                              const float* __restrict__ pwr,
                                              const float* __restrict__ pwi,
                                              u16* __restrict__ Abig, int b) {
    __shared__ float A[2][64][64];
    __shared__ float rq[2][64], rk[2][64];
    {
        int ch = threadIdx.x & 127, d = threadIdx.x >> 7;
        float s = rnsum[((size_t)b * 128 + ch) * 2 + d];
        float r = 1.0f / fmaxf(sqrtf(s), 1e-12f);
        if (ch < 64) rq[d][ch] = r; else rk[d][ch - 64] = r;
    }
    __syncthreads();
    for (int i = threadIdx.x; i < 2 * 64 * 64; i += 256) {
        int d = i >> 12, cq = (i >> 6) & 63, ce = i & 63;
        float v = attn[(b * 2 + d) * 4096 + cq * 64 + ce];
        A[d][cq][ce] = v * rq[d][cq] * rk[d][ce];
    }
    __syncthreads();
    if (threadIdx.x < 128) {
        int d = threadIdx.x >> 6, cq = threadIdx.x & 63;
        float m = -1e30f;
        for (int e = 0; e < 64; ++e) m = fmaxf(m, A[d][cq][e]);
        float s = 0.f;
        for (int e = 0; e < 64; ++e) { float ev = __expf(A[d][cq][e] - m); A[d][cq][e] = ev; s += ev; }
        float r = 1.0f / s;
        for (int e = 0; e < 64; ++e) A[d][cq][e] *= r;
    }
    __syncthreads();
    u16* AB = Abig + (size_t)b * 16384;
    for (int i = threadIdx.x; i < 4096; i += 256) {
        int co = i >> 6, e = i & 63;
        float m1 = 0.f, m2 = 0.f, m3 = 0.f, m4 = 0.f;
        for (int c = 0; c < 64; ++c) {
            float pr = pwr[co * 64 + c], pi = pwi[co * 64 + c];
            float a0 = A[0][c][e], a1 = A[1][c][e];
            m1 = fmaf(pr, a0, m1);
            m2 = fmaf(pi, a1, m2);
            m3 = fmaf(pr, a1, m3);
            m4 = fmaf(pi, a0, m4);
        }
        AB[(2 * co) * 128 + 2 * e]         = f2bf(m1);
        AB[(2 * co) * 128 + 2 * e + 1]     = f2bf(-m2);
        AB[(2 * co + 1) * 128 + 2 * e]     = f2bf(m4);
        AB[(2 * co + 1) * 128 + 2 * e + 1] = f2bf(m3);
    }
}

// ---------------- Kernel E: transpose vpack [64][HWS] u32 -> vT [HWS][64] u32 ----------------
__global__ __launch_bounds__(256) void k_vt(const u32* __restrict__ in,
                                            u32* __restrict__ outp) {
    __shared__ u32 tile[64][65];
    int p0 = blockIdx.x << 6;
    int t = threadIdx.x;
    for (int i = t; i < 4096; i += 256) {
        int e = i >> 6, c = i & 63;
        tile[e][c] = in[(size_t)e * HWS + p0 + c];
    }
    __syncthreads();
    for (int i = t; i < 4096; i += 256) {
        int r = i >> 6, e = i & 63;
        outp[(size_t)(p0 + r) * 64 + e] = tile[e][r];
    }
}

// ---------------- Kernel F: out = A_big * vT via MFMA (no LDS) ----------------
// vT as u16 [HWS][128]; A_big[b] [128][128] u16; outb f32 [64][HWS][2]
__global__ __launch_bounds__(256) void k_out(const u16* __restrict__ Abig,
                                             const u16* __restrict__ vT,
                                             float* __restrict__ outb) {
    const int p0 = blockIdx.x << 6;
    const int t = threadIdx.x, lane = t & 63, w = t >> 6;
    const int l15 = lane & 15, l4 = lane >> 4;

    bf16x8 Af[2][4];
#pragma unroll
    for (int cf = 0; cf < 2; ++cf)
#pragma unroll
        for (int ks = 0; ks < 4; ++ks)
            Af[cf][ks] = *(const bf16x8*)&Abig[(size_t)(32 * w + 16 * cf + l15) * 128 + 32 * ks + 8 * l4];

    f32x4 zz = {0.f, 0.f, 0.f, 0.f};
    f32x4 acc[2][4];
#pragma unroll
    for (int cf = 0; cf < 2; ++cf)
#pragma unroll
        for (int nf = 0; nf < 4; ++nf) acc[cf][nf] = zz;

#pragma unroll
    for (int ks = 0; ks < 4; ++ks) {
        bf16x8 Bf[4];
#pragma unroll
        for (int nf = 0; nf < 4; ++nf)
            Bf[nf] = *(const bf16x8*)&vT[(size_t)(p0 + 16 * nf + l15) * 128 + 32 * ks + 8 * l4];
#pragma unroll
        for (int cf = 0; cf < 2; ++cf)
#pragma unroll
            for (int nf = 0; nf < 4; ++nf)
                acc[cf][nf] = __builtin_amdgcn_mfma_f32_16x16x32_bf16(Af[cf][ks], Bf[nf], acc[cf][nf], 0, 0, 0);
    }

    float2* o2 = (float2*)outb;
#pragma unroll
    for (int cf = 0; cf < 2; ++cf)
#pragma unroll
        for (int nf = 0; nf < 4; ++nf) {
            int co = 16 * w + 8 * cf + 2 * l4;
            int p = p0 + 16 * nf + l15;
            o2[(size_t)co * HWS + p]       = make_float2(acc[cf][nf][0], acc[cf][nf][1]);
            o2[(size_t)(co + 1) * HWS + p] = make_float2(acc[cf][nf][2], acc[cf][nf][3]);
        }
}

extern "C" void kernel_launch(void* const* d_in, const int* in_sizes, int n_in,
                              void* d_out, int out_size, void* d_ws, size_t ws_size,
                              hipStream_t stream) {
    const float* x      = (const float*)d_in[0];
    const float* qkv_wr = (const float*)d_in[1];
    const float* qkv_wi = (const float*)d_in[2];
    const float* dw_wr  = (const float*)d_in[3];
    const float* dw_wi  = (const float*)d_in[4];
    const float* p_wr   = (const float*)d_in[5];
    const float* p_wi   = (const float*)d_in[6];
    float* out = (float*)d_out;

    int R;
    if (ws_size >= 104ull * 1000 * 1000)      R = 256;
    else if (ws_size >= 62ull * 1000 * 1000)  R = 128;
    else                                      R = 64;
    const int S = 256 / R;
    const int SP = R << 8;
    int lsh = 13;                    // log2(SP/2)
    if (R == 128) lsh = 14;
    if (R == 256) lsh = 15;

    char* base = (char*)d_ws;
    size_t qs_bytes = (size_t)192 * (R + 2) * 256 * 4;
    size_t dw_bytes = (size_t)4 * 64 * SP * 2;
    size_t vt_bytes = (size_t)HWS * 64 * 4;
    u32*   qs_u  = (u32*)base;
    u16*   dwp   = (u16*)(base + qs_bytes);
    u32*   vT    = (u32*)(base + qs_bytes + dw_bytes);
    u16*   wbf   = (u16*)(base + qs_bytes + dw_bytes + vt_bytes);
    u16*   Abig  = (u16*)(base + qs_bytes + dw_bytes + vt_bytes + 73728);
    float* rnsum = (float*)(base + qs_bytes + dw_bytes + vt_bytes + 73728 + 65536);
    float* attn  = rnsum + 512;

    k_wcvt<<<48, 256, 0, stream>>>(qkv_wr, qkv_wi, wbf);
    k_zero<<<66, 256, 0, stream>>>(rnsum, 512 + 16384);

    for (int b = 0; b < 2; ++b) {
        const float* xb = x + (size_t)b * 64 * HWS * 2;
        u32* vpack = (u32*)(out + (size_t)b * 64 * HWS * 2);
        for (int s = 0; s < S; ++s) {
            k_qkv<<<dim3((R + 2) * 4, 3), 256, 0, stream>>>(xb, wbf, qs_u, s, R);
            k_dw<<<(192 * SP / 2) / 256, 256, 0, stream>>>(qs_u, dw_wr, dw_wi,
                                                           dwp, vpack, s, R, lsh);
            k_qk<<<dim3(32, 2), 256, 0, stream>>>(dwp, rnsum, attn, b, SP);
        }
        k_soft<<<1, 256, 0, stream>>>(attn, rnsum, p_wr, p_wi, Abig, b);
        k_vt<<<1024, 256, 0, stream>>>(vpack, vT);
        k_out<<<1024, 256, 0, stream>>>(Abig + (size_t)b * 16384, (const u16*)vT,
                                        out + (size_t)b * 64 * HWS * 2);
    }
}

// Round 5
// 330.633 us; speedup vs baseline: 4.1955x; 1.4457x over previous
//
#include <hip/hip_runtime.h>

#define HWS 65536   // 256*256

typedef __attribute__((ext_vector_type(8))) short bf16x8;
typedef __attribute__((ext_vector_type(4))) float f32x4;
typedef unsigned int u32;
typedef unsigned short u16;

__device__ __forceinline__ u16 f2bf(float x) {
    u32 u = __float_as_uint(x);
    return (u16)((u + 0x7fffu + ((u >> 16) & 1u)) >> 16);
}
__device__ __forceinline__ float bf2f(u32 h) { return __uint_as_float(h << 16); }
__device__ __forceinline__ u32 pack2(float a, float b) {
    return (u32)f2bf(a) | ((u32)f2bf(b) << 16);
}

// ---------------- tiny helpers ----------------
__global__ void k_zero(float* __restrict__ p, int n) {
    int i = blockIdx.x * 256 + threadIdx.x;
    if (i < n) p[i] = 0.f;
}

// convert qkv weights to bf16 planes: [Wr | Wi | -Wi], each [192][64]
__global__ void k_wcvt(const float* __restrict__ wr, const float* __restrict__ wi,
                       u16* __restrict__ wbf) {
    int i = blockIdx.x * 256 + threadIdx.x;
    if (i < 12288) {
        wbf[i]         = f2bf(wr[i]);
        wbf[12288 + i] = f2bf(wi[i]);
        wbf[24576 + i] = f2bf(-wi[i]);
    }
}

// ---------------- Kernel A: qkv 1x1 complex conv via bf16 MFMA ----------------
// x_b: [64][HWS][2] f32; qs: [192][(R+2)*256] packed bf16 (r,i); strip s covers w in [s*R-1, s*R+R]
// grid: (3 cog, (R+2)*4 ptile) -- cog fastest so x-tile reuse hits L2
__global__ __launch_bounds__(256) void k_qkv(const float* __restrict__ x,
                                             const u16* __restrict__ wbf,
                                             u32* __restrict__ qs,
                                             int s, int R) {
    __shared__ u16 Wr[64][72], Wi[64][72], Wn[64][72];
    __shared__ u16 Xr[64][72], Xi[64][72];
    const int cog = blockIdx.x, ptile = blockIdx.y;
    const int row = ptile >> 2, h0 = (ptile & 3) << 6;
    const int w = s * R - 1 + row;
    const bool valid = (unsigned)w < 256u;
    const int SPz = (R + 2) << 8;
    const int t = threadIdx.x;

    for (int i = t; i < 4096; i += 256) {
        int co = i >> 6, ci = i & 63;
        int g = (cog * 64 + co) * 64 + ci;
        Wr[co][ci] = wbf[g];
        Wi[co][ci] = wbf[12288 + g];
        Wn[co][ci] = wbf[24576 + g];
    }
    const float2* x2 = (const float2*)x;
    for (int i = t; i < 4096; i += 256) {
        int ci = i >> 6, pp = i & 63;
        float2 v = valid ? x2[(size_t)ci * HWS + w * 256 + h0 + pp]
                         : make_float2(0.f, 0.f);
        Xr[pp][ci] = f2bf(v.x);
        Xi[pp][ci] = f2bf(v.y);
    }
    __syncthreads();

    const int lane = t & 63, wid = t >> 6;
    const int wy = wid >> 1, wx = wid & 1;
    const int l15 = lane & 15, l4 = lane >> 4;

    bf16x8 Afr[2][2], Afi[2][2], Afn[2][2], Bfr[2][2], Bfi[2][2];
#pragma unroll
    for (int cf = 0; cf < 2; ++cf)
#pragma unroll
        for (int ks = 0; ks < 2; ++ks) {
            int r0 = 32 * wy + 16 * cf + l15, c0 = 32 * ks + 8 * l4;
            Afr[cf][ks] = *(const bf16x8*)&Wr[r0][c0];
            Afi[cf][ks] = *(const bf16x8*)&Wi[r0][c0];
            Afn[cf][ks] = *(const bf16x8*)&Wn[r0][c0];
        }
#pragma unroll
    for (int pf = 0; pf < 2; ++pf)
#pragma unroll
        for (int ks = 0; ks < 2; ++ks) {
            int r0 = 32 * wx + 16 * pf + l15, c0 = 32 * ks + 8 * l4;
            Bfr[pf][ks] = *(const bf16x8*)&Xr[r0][c0];
            Bfi[pf][ks] = *(const bf16x8*)&Xi[r0][c0];
        }

    f32x4 zz = {0.f, 0.f, 0.f, 0.f};
    f32x4 accr[2][2], acci[2][2];
#pragma unroll
    for (int cf = 0; cf < 2; ++cf)
#pragma unroll
        for (int pf = 0; pf < 2; ++pf) { accr[cf][pf] = zz; acci[cf][pf] = zz; }

#pragma unroll
    for (int ks = 0; ks < 2; ++ks)
#pragma unroll
        for (int cf = 0; cf < 2; ++cf)
#pragma unroll
            for (int pf = 0; pf < 2; ++pf) {
                accr[cf][pf] = __builtin_amdgcn_mfma_f32_16x16x32_bf16(Afr[cf][ks], Bfr[pf][ks], accr[cf][pf], 0, 0, 0);
                accr[cf][pf] = __builtin_amdgcn_mfma_f32_16x16x32_bf16(Afn[cf][ks], Bfi[pf][ks], accr[cf][pf], 0, 0, 0);
                acci[cf][pf] = __builtin_amdgcn_mfma_f32_16x16x32_bf16(Afi[cf][ks], Bfr[pf][ks], acci[cf][pf], 0, 0, 0);
                acci[cf][pf] = __builtin_amdgcn_mfma_f32_16x16x32_bf16(Afr[cf][ks], Bfi[pf][ks], acci[cf][pf], 0, 0, 0);
            }

#pragma unroll
    for (int cf = 0; cf < 2; ++cf)
#pragma unroll
        for (int pf = 0; pf < 2; ++pf)
#pragma unroll
            for (int r = 0; r < 4; ++r) {
                int co = cog * 64 + 32 * wy + 16 * cf + 4 * l4 + r;
                int p  = row * 256 + h0 + 32 * wx + 16 * pf + l15;
                qs[(size_t)co * SPz + p] = pack2(accr[cf][pf][r], acci[cf][pf][r]);
            }
}

// ---------------- Kernel B: depthwise 3x3 complex conv, 2 pixels/thread ----------------
// qs packed [192][(R+2)*256]; ch<128 -> dwp planes [4][64][SP] u16 (q_r,q_i,k_r,k_i);
// ch>=128 -> vpack [64][HWS] u32 (r,i) inside d_out batch region
__global__ __launch_bounds__(256) void k_dw(const u32* __restrict__ qs,
                                            const float* __restrict__ wr,
                                            const float* __restrict__ wi,
                                            u16* __restrict__ dwp,
                                            u32* __restrict__ vpack,
                                            int s, int R, int lsh) {
    int idx = blockIdx.x * 256 + threadIdx.x;   // over 192*SP/2
    int SP = R << 8;
    int p2 = (idx & ((SP >> 1) - 1)) << 1;
    int ch = idx >> lsh;
    int r64 = p2 >> 8, h = p2 & 255;
    int SPz = (R + 2) << 8;
    const u32* src = qs + (size_t)ch * SPz + r64 * 256;

    float wrl[9], wil[9];
#pragma unroll
    for (int tt = 0; tt < 9; ++tt) { wrl[tt] = wr[ch * 9 + tt]; wil[tt] = wi[ch * 9 + tt]; }

    float a0r = 0.f, a0i = 0.f, a1r = 0.f, a1i = 0.f;
#pragma unroll
    for (int du = 0; du < 3; ++du) {
#pragma unroll
        for (int c4 = 0; c4 < 4; ++c4) {
            int hh = h - 1 + c4;
            u32 u = ((unsigned)hh < 256u) ? src[du * 256 + hh] : 0u;
            float vr = bf2f(u & 0xffffu), vi = bf2f(u >> 16);
            if (c4 < 3) {
                float w0 = wrl[du * 3 + c4], w1 = wil[du * 3 + c4];
                a0r = fmaf(w0, vr, a0r); a0r = fmaf(-w1, vi, a0r);
                a0i = fmaf(w1, vr, a0i); a0i = fmaf(w0, vi, a0i);
            }
            if (c4 > 0) {
                float w0 = wrl[du * 3 + c4 - 1], w1 = wil[du * 3 + c4 - 1];
                a1r = fmaf(w0, vr, a1r); a1r = fmaf(-w1, vi, a1r);
                a1i = fmaf(w1, vr, a1i); a1i = fmaf(w0, vi, a1i);
            }
        }
    }

    if (ch < 128) {
        int pl = (ch < 64) ? 0 : 2;
        int row = ch & 63;
        u16* base = dwp + ((size_t)pl * 64 + row) * SP + p2;
        *(u32*)base          = pack2(a0r, a1r);
        *(u32*)(base + (size_t)64 * SP) = pack2(a0i, a1i);   // imag plane (pl+1)
    } else {
        int e = ch - 128;
        uint2 vv = make_uint2(pack2(a0r, a0i), pack2(a1r, a1i));
        *(uint2*)&vpack[(size_t)e * HWS + (s * R + r64) * 256 + h] = vv;
    }
}

// ---------------- Kernel C: q k^T + fused sumsq via MFMA (no LDS) ----------------
// dwp planes [4][64][SP]; rnsum [2][128][2]; attn [2][2][64][64]
__global__ __launch_bounds__(256) void k_qk(const u16* __restrict__ dwp,
                                            float* __restrict__ rnsum,
                                            float* __restrict__ attn,
                                            int b, int SP) {
    const int chunk = blockIdx.x;        // 0..31
    const int d = blockIdx.y;
    const int Kc = SP >> 5;
    const int kc0 = chunk * Kc;
    const u16* qp = dwp + (size_t)d * 64 * SP;
    const u16* kp = dwp + (size_t)(2 + d) * 64 * SP;

    const int t = threadIdx.x, lane = t & 63, wid = t >> 6;
    const int wy = wid >> 1, wx = wid & 1;
    const int l15 = lane & 15, l4 = lane >> 4;

    f32x4 zz = {0.f, 0.f, 0.f, 0.f};
    f32x4 acc[2][2] = {{zz, zz}, {zz, zz}};
    float sq[2] = {0.f, 0.f}, sk[2] = {0.f, 0.f};

    const int iters = Kc >> 5;
    for (int ks = 0; ks < iters; ++ks) {
        int k0 = kc0 + ks * 32 + 8 * l4;
        bf16x8 aq[2], bk[2];
#pragma unroll
        for (int cf = 0; cf < 2; ++cf)
            aq[cf] = *(const bf16x8*)&qp[(size_t)(32 * wy + 16 * cf + l15) * SP + k0];
#pragma unroll
        for (int ef = 0; ef < 2; ++ef)
            bk[ef] = *(const bf16x8*)&kp[(size_t)(32 * wx + 16 * ef + l15) * SP + k0];

        if (wx == 0)
#pragma unroll
            for (int cf = 0; cf < 2; ++cf)
#pragma unroll
                for (int j = 0; j < 8; ++j) {
                    float f = bf2f((u16)aq[cf][j]);
                    sq[cf] = fmaf(f, f, sq[cf]);
                }
        if (wy == 0)
#pragma unroll
            for (int ef = 0; ef < 2; ++ef)
#pragma unroll
                for (int j = 0; j < 8; ++j) {
                    float f = bf2f((u16)bk[ef][j]);
                    sk[ef] = fmaf(f, f, sk[ef]);
                }

#pragma unroll
        for (int cf = 0; cf < 2; ++cf)
#pragma unroll
            for (int ef = 0; ef < 2; ++ef)
                acc[cf][ef] = __builtin_amdgcn_mfma_f32_16x16x32_bf16(aq[cf], bk[ef], acc[cf][ef], 0, 0, 0);
    }

#pragma unroll
    for (int cf = 0; cf < 2; ++cf)
#pragma unroll
        for (int ef = 0; ef < 2; ++ef)
#pragma unroll
            for (int r = 0; r < 4; ++r) {
                int cq = 32 * wy + 16 * cf + 4 * l4 + r;
                int ce = 32 * wx + 16 * ef + l15;
                atomicAdd(&attn[((b * 2 + d) * 64 + cq) * 64 + ce], acc[cf][ef][r]);
            }

    if (wx == 0)
#pragma unroll
        for (int cf = 0; cf < 2; ++cf) {
            float v = sq[cf];
            v += __shfl_xor(v, 16);
            v += __shfl_xor(v, 32);
            if (lane < 16)
                atomicAdd(&rnsum[((size_t)b * 128 + 32 * wy + 16 * cf + lane) * 2 + d], v);
        }
    if (wy == 0)
#pragma unroll
        for (int ef = 0; ef < 2; ++ef) {
            float v = sk[ef];
            v += __shfl_xor(v, 16);
            v += __shfl_xor(v, 32);
            if (lane < 16)
                atomicAdd(&rnsum[((size_t)b * 128 + 64 + 32 * wx + 16 * ef + lane) * 2 + d], v);
        }
}

// ---------------- Kernel D1: scale + row softmax -> P (grid (2b,2d), 64 thr) ----------------
__global__ __launch_bounds__(64) void k_prob(const float* __restrict__ attn,
                                             const float* __restrict__ rnsum,
                                             float* __restrict__ P) {
    int b = blockIdx.x, d = blockIdx.y;
    int t = threadIdx.x;
    __shared__ float rks[64];
    float sk = rnsum[((size_t)b * 128 + 64 + t) * 2 + d];
    rks[t] = 1.0f / fmaxf(sqrtf(sk), 1e-12f);
    float sq = rnsum[((size_t)b * 128 + t) * 2 + d];
    float rq = 1.0f / fmaxf(sqrtf(sq), 1e-12f);
    __syncthreads();

    const float* arow = attn + ((size_t)(b * 2 + d) * 64 + t) * 64;
    float v[64];
    float m = -1e30f;
#pragma unroll
    for (int e = 0; e < 64; ++e) { v[e] = arow[e] * rq * rks[e]; m = fmaxf(m, v[e]); }
    float ssum = 0.f;
#pragma unroll
    for (int e = 0; e < 64; ++e) { v[e] = __expf(v[e] - m); ssum += v[e]; }
    float r = 1.0f / ssum;
    float* prow = P + ((size_t)(b * 2 + d) * 64 + t) * 64;
#pragma unroll
    for (int e = 0; e < 64; ++e) prow[e] = v[e] * r;
}

// ---------------- Kernel D2: build A_big from P and proj weights ----------------
// grid (16, 2b), 256 thr; each thread one (co,e)
// A_big[b] [128][128] u16: [2co][2e]=M1 [2co][2e+1]=-M2 [2co+1][2e]=M4 [2co+1][2e+1]=M3
__global__ __launch_bounds__(256) void k_M(const float* __restrict__ P,
                                           const float* __restrict__ pwr,
                                           const float* __restrict__ pwi,
                                           u16* __restrict__ Abig) {
    int b = blockIdx.y;
    int pair = blockIdx.x * 256 + threadIdx.x;   // 0..4095
    __shared__ float P0[64][64], P1[64][64];     // 32 KB
    __shared__ float Wr[64][64], Wi2[64][64];    // 32 KB
    for (int i = threadIdx.x; i < 4096; i += 256) {
        P0[i >> 6][i & 63] = P[(size_t)(b * 2 + 0) * 4096 + i];
        P1[i >> 6][i & 63] = P[(size_t)(b * 2 + 1) * 4096 + i];
        Wr[i >> 6][i & 63] = pwr[i];
        Wi2[i >> 6][i & 63] = pwi[i];
    }
    __syncthreads();
    int co = pair >> 6, e = pair & 63;
    float m1 = 0.f, m2 = 0.f, m3 = 0.f, m4 = 0.f;
#pragma unroll 8
    for (int c = 0; c < 64; ++c) {
        float pr = Wr[co][c], pi = Wi2[co][c];
        float a0 = P0[c][e], a1 = P1[c][e];
        m1 = fmaf(pr, a0, m1);
        m2 = fmaf(pi, a1, m2);
        m3 = fmaf(pr, a1, m3);
        m4 = fmaf(pi, a0, m4);
    }
    u16* AB = Abig + (size_t)b * 16384;
    AB[(2 * co) * 128 + 2 * e]         = f2bf(m1);
    AB[(2 * co) * 128 + 2 * e + 1]     = f2bf(-m2);
    AB[(2 * co + 1) * 128 + 2 * e]     = f2bf(m4);
    AB[(2 * co + 1) * 128 + 2 * e + 1] = f2bf(m3);
}

// ---------------- Kernel E: transpose vpack [64][HWS] u32 -> vT [HWS][64] u32 ----------------
__global__ __launch_bounds__(256) void k_vt(const u32* __restrict__ in,
                                            u32* __restrict__ outp) {
    __shared__ u32 tile[64][65];
    int p0 = blockIdx.x << 6;
    int t = threadIdx.x;
    for (int i = t; i < 4096; i += 256) {
        int e = i >> 6, c = i & 63;
        tile[e][c] = in[(size_t)e * HWS + p0 + c];
    }
    __syncthreads();
    for (int i = t; i < 4096; i += 256) {
        int r = i >> 6, e = i & 63;
        outp[(size_t)(p0 + r) * 64 + e] = tile[e][r];
    }
}

// ---------------- Kernel F: out = A_big * vT via MFMA (no LDS) ----------------
// vT as u16 [HWS][128]; A_big[b] [128][128] u16; outb f32 [64][HWS][2]
__global__ __launch_bounds__(256) void k_out(const u16* __restrict__ Abig,
                                             const u16* __restrict__ vT,
                                             float* __restrict__ outb) {
    const int p0 = blockIdx.x << 6;
    const int t = threadIdx.x, lane = t & 63, w = t >> 6;
    const int l15 = lane & 15, l4 = lane >> 4;

    bf16x8 Af[2][4];
#pragma unroll
    for (int cf = 0; cf < 2; ++cf)
#pragma unroll
        for (int ks = 0; ks < 4; ++ks)
            Af[cf][ks] = *(const bf16x8*)&Abig[(size_t)(32 * w + 16 * cf + l15) * 128 + 32 * ks + 8 * l4];

    f32x4 zz = {0.f, 0.f, 0.f, 0.f};
    f32x4 acc[2][4];
#pragma unroll
    for (int cf = 0; cf < 2; ++cf)
#pragma unroll
        for (int nf = 0; nf < 4; ++nf) acc[cf][nf] = zz;

#pragma unroll
    for (int ks = 0; ks < 4; ++ks) {
        bf16x8 Bf[4];
#pragma unroll
        for (int nf = 0; nf < 4; ++nf)
            Bf[nf] = *(const bf16x8*)&vT[(size_t)(p0 + 16 * nf + l15) * 128 + 32 * ks + 8 * l4];
#pragma unroll
        for (int cf = 0; cf < 2; ++cf)
#pragma unroll
            for (int nf = 0; nf < 4; ++nf)
                acc[cf][nf] = __builtin_amdgcn_mfma_f32_16x16x32_bf16(Af[cf][ks], Bf[nf], acc[cf][nf], 0, 0, 0);
    }

    float2* o2 = (float2*)outb;
#pragma unroll
    for (int cf = 0; cf < 2; ++cf)
#pragma unroll
        for (int nf = 0; nf < 4; ++nf) {
            int co = 16 * w + 8 * cf + 2 * l4;
            int p = p0 + 16 * nf + l15;
            o2[(size_t)co * HWS + p]       = make_float2(acc[cf][nf][0], acc[cf][nf][1]);
            o2[(size_t)(co + 1) * HWS + p] = make_float2(acc[cf][nf][2], acc[cf][nf][3]);
        }
}

extern "C" void kernel_launch(void* const* d_in, const int* in_sizes, int n_in,
                              void* d_out, int out_size, void* d_ws, size_t ws_size,
                              hipStream_t stream) {
    const float* x      = (const float*)d_in[0];
    const float* qkv_wr = (const float*)d_in[1];
    const float* qkv_wi = (const float*)d_in[2];
    const float* dw_wr  = (const float*)d_in[3];
    const float* dw_wi  = (const float*)d_in[4];
    const float* p_wr   = (const float*)d_in[5];
    const float* p_wi   = (const float*)d_in[6];
    float* out = (float*)d_out;

    int R;
    if (ws_size >= 104ull * 1000 * 1000)      R = 256;
    else if (ws_size >= 62ull * 1000 * 1000)  R = 128;
    else                                      R = 64;
    const int S = 256 / R;
    const int SP = R << 8;
    int lsh = 13;                    // log2(SP/2)
    if (R == 128) lsh = 14;
    if (R == 256) lsh = 15;

    char* base = (char*)d_ws;
    size_t qs_bytes = (size_t)192 * (R + 2) * 256 * 4;
    size_t dw_bytes = (size_t)4 * 64 * SP * 2;
    size_t vt_bytes = (size_t)HWS * 64 * 4;
    u32*   qs_u  = (u32*)base;
    u16*   dwp   = (u16*)(base + qs_bytes);
    u32*   vT    = (u32*)(base + qs_bytes + dw_bytes);
    u16*   wbf   = (u16*)(base + qs_bytes + dw_bytes + vt_bytes);
    u16*   Abig  = (u16*)(base + qs_bytes + dw_bytes + vt_bytes + 73728);
    float* rnsum = (float*)(base + qs_bytes + dw_bytes + vt_bytes + 73728 + 65536);
    float* attn  = rnsum + 512;
    float* Pbuf  = attn + 16384;

    k_wcvt<<<48, 256, 0, stream>>>(qkv_wr, qkv_wi, wbf);
    k_zero<<<66, 256, 0, stream>>>(rnsum, 512 + 16384);

    for (int b = 0; b < 2; ++b) {
        const float* xb = x + (size_t)b * 64 * HWS * 2;
        u32* vpack = (u32*)(out + (size_t)b * 64 * HWS * 2);
        for (int s = 0; s < S; ++s) {
            k_qkv<<<dim3(3, (R + 2) * 4), 256, 0, stream>>>(xb, wbf, qs_u, s, R);
            k_dw<<<(192 * SP / 2) / 256, 256, 0, stream>>>(qs_u, dw_wr, dw_wi,
                                                           dwp, vpack, s, R, lsh);
            k_qk<<<dim3(32, 2), 256, 0, stream>>>(dwp, rnsum, attn, b, SP);
        }
    }
    k_prob<<<dim3(2, 2), 64, 0, stream>>>(attn, rnsum, Pbuf);
    k_M<<<dim3(16, 2), 256, 0, stream>>>(Pbuf, p_wr, p_wi, Abig);
    for (int b = 0; b < 2; ++b) {
        u32* vpack = (u32*)(out + (size_t)b * 64 * HWS * 2);
        k_vt<<<1024, 256, 0, stream>>>(vpack, vT);
        k_out<<<1024, 256, 0, stream>>>(Abig + (size_t)b * 16384, (const u16*)vT,
                                        out + (size_t)b * 64 * HWS * 2);
    }
}

// Round 6
// 305.617 us; speedup vs baseline: 4.5389x; 1.0819x over previous
//
#include <hip/hip_runtime.h>

#define HWS 65536   // 256*256

typedef __attribute__((ext_vector_type(8))) short bf16x8;
typedef __attribute__((ext_vector_type(4))) float f32x4;
typedef unsigned int u32;
typedef unsigned short u16;

__device__ __forceinline__ u16 f2bf(float x) {
    u32 u = __float_as_uint(x);
    return (u16)((u + 0x7fffu + ((u >> 16) & 1u)) >> 16);
}
__device__ __forceinline__ float bf2f(u32 h) { return __uint_as_float(h << 16); }
__device__ __forceinline__ u32 pack2(float a, float b) {
    return (u32)f2bf(a) | ((u32)f2bf(b) << 16);
}

// ---------------- tiny helpers ----------------
__global__ void k_zero(float* __restrict__ p, int n) {
    int i = blockIdx.x * 256 + threadIdx.x;
    if (i < n) p[i] = 0.f;
}

// convert qkv weights to bf16 planes: [Wr | Wi | -Wi], each [192][64]
__global__ void k_wcvt(const float* __restrict__ wr, const float* __restrict__ wi,
                       u16* __restrict__ wbf) {
    int i = blockIdx.x * 256 + threadIdx.x;
    if (i < 12288) {
        wbf[i]         = f2bf(wr[i]);
        wbf[12288 + i] = f2bf(wi[i]);
        wbf[24576 + i] = f2bf(-wi[i]);
    }
}

// ---------------- Kernel X: transpose+convert x -> xTr/xTi bf16 [HWS][64] ----------------
__global__ __launch_bounds__(256) void k_xt(const float* __restrict__ x,
                                            u16* __restrict__ xTr,
                                            u16* __restrict__ xTi) {
    __shared__ u16 Tr[64][73], Ti[64][73];
    int p0 = blockIdx.x << 6;
    int t = threadIdx.x;
    const float2* x2 = (const float2*)x;
    for (int i = t; i < 4096; i += 256) {
        int ci = i >> 6, c = i & 63;
        float2 v = x2[(size_t)ci * HWS + p0 + c];
        Tr[c][ci] = f2bf(v.x);
        Ti[c][ci] = f2bf(v.y);
    }
    __syncthreads();
    for (int i = t; i < 4096; i += 256) {
        int rr = i >> 6, ci = i & 63;
        xTr[(size_t)(p0 + rr) * 64 + ci] = Tr[rr][ci];
        xTi[(size_t)(p0 + rr) * 64 + ci] = Ti[rr][ci];
    }
}

// ---------------- Kernel A: qkv 1x1 complex conv, global->MFMA, no LDS ----------------
// xTr/xTi: [HWS][64] bf16; wbf planes [192][64]; qs: [192][(R+2)*256] packed bf16 (r,i)
// grid (6 cog, R+2 row-tiles); 4 waves, each wave 64 positions of the row.
__global__ __launch_bounds__(256) void k_qkv(const u16* __restrict__ xTr,
                                             const u16* __restrict__ xTi,
                                             const u16* __restrict__ wbf,
                                             u32* __restrict__ qs,
                                             int s, int R) {
    const int cog = blockIdx.x;          // 0..5, 32 co each
    const int rt  = blockIdx.y;          // 0..R+1
    const int w   = s * R - 1 + rt;      // image row (may be OOB -> zeros)
    const int SPz = (R + 2) << 8;
    const int t = threadIdx.x, lane = t & 63, wv = t >> 6;
    const int l15 = lane & 15, l4 = lane >> 4;
    const bool valid = (unsigned)w < 256u;

    bf16x8 Ar[2][2], Ai[2][2], An[2][2];
#pragma unroll
    for (int cf = 0; cf < 2; ++cf)
#pragma unroll
        for (int ks = 0; ks < 2; ++ks) {
            size_t off = (size_t)(cog * 32 + 16 * cf + l15) * 64 + 32 * ks + 8 * l4;
            Ar[cf][ks] = *(const bf16x8*)&wbf[off];
            Ai[cf][ks] = *(const bf16x8*)&wbf[12288 + off];
            An[cf][ks] = *(const bf16x8*)&wbf[24576 + off];
        }

    const f32x4 zz = {0.f, 0.f, 0.f, 0.f};
#pragma unroll
    for (int pf = 0; pf < 4; ++pf) {
        f32x4 cr[2] = {zz, zz}, cim[2] = {zz, zz};
        if (valid) {
            bf16x8 br[2], bi[2];
#pragma unroll
            for (int ks = 0; ks < 2; ++ks) {
                size_t boff = (size_t)(w * 256 + wv * 64 + pf * 16 + l15) * 64
                              + 32 * ks + 8 * l4;
                br[ks] = *(const bf16x8*)&xTr[boff];
                bi[ks] = *(const bf16x8*)&xTi[boff];
            }
#pragma unroll
            for (int ks = 0; ks < 2; ++ks)
#pragma unroll
                for (int cf = 0; cf < 2; ++cf) {
                    cr[cf]  = __builtin_amdgcn_mfma_f32_16x16x32_bf16(Ar[cf][ks], br[ks], cr[cf], 0, 0, 0);
                    cr[cf]  = __builtin_amdgcn_mfma_f32_16x16x32_bf16(An[cf][ks], bi[ks], cr[cf], 0, 0, 0);
                    cim[cf] = __builtin_amdgcn_mfma_f32_16x16x32_bf16(Ai[cf][ks], br[ks], cim[cf], 0, 0, 0);
                    cim[cf] = __builtin_amdgcn_mfma_f32_16x16x32_bf16(Ar[cf][ks], bi[ks], cim[cf], 0, 0, 0);
                }
        }
        int p = rt * 256 + wv * 64 + pf * 16 + l15;
#pragma unroll
        for (int cf = 0; cf < 2; ++cf)
#pragma unroll
            for (int r = 0; r < 4; ++r) {
                int co = cog * 32 + 16 * cf + 4 * l4 + r;
                qs[(size_t)co * SPz + p] = valid ? pack2(cr[cf][r], cim[cf][r]) : 0u;
            }
    }
}

// ---------------- Kernel B: depthwise 3x3 complex conv, 2 pixels/thread ----------------
// qs packed [192][(R+2)*256]; ch<128 -> dwp planes [4][64][SP] u16 (q_r,q_i,k_r,k_i);
// ch>=128 -> vpack [64][HWS] u32 (r,i) inside d_out batch region
__global__ __launch_bounds__(256) void k_dw(const u32* __restrict__ qs,
                                            const float* __restrict__ wr,
                                            const float* __restrict__ wi,
                                            u16* __restrict__ dwp,
                                            u32* __restrict__ vpack,
                                            int s, int R, int lsh) {
    int idx = blockIdx.x * 256 + threadIdx.x;   // over 192*SP/2
    int SP = R << 8;
    int p2 = (idx & ((SP >> 1) - 1)) << 1;
    int ch = idx >> lsh;
    int r64 = p2 >> 8, h = p2 & 255;
    int SPz = (R + 2) << 8;
    const u32* src = qs + (size_t)ch * SPz + r64 * 256;

    float wrl[9], wil[9];
#pragma unroll
    for (int tt = 0; tt < 9; ++tt) { wrl[tt] = wr[ch * 9 + tt]; wil[tt] = wi[ch * 9 + tt]; }

    float a0r = 0.f, a0i = 0.f, a1r = 0.f, a1i = 0.f;
#pragma unroll
    for (int du = 0; du < 3; ++du) {
#pragma unroll
        for (int c4 = 0; c4 < 4; ++c4) {
            int hh = h - 1 + c4;
            u32 u = ((unsigned)hh < 256u) ? src[du * 256 + hh] : 0u;
            float vr = bf2f(u & 0xffffu), vi = bf2f(u >> 16);
            if (c4 < 3) {
                float w0 = wrl[du * 3 + c4], w1 = wil[du * 3 + c4];
                a0r = fmaf(w0, vr, a0r); a0r = fmaf(-w1, vi, a0r);
                a0i = fmaf(w1, vr, a0i); a0i = fmaf(w0, vi, a0i);
            }
            if (c4 > 0) {
                float w0 = wrl[du * 3 + c4 - 1], w1 = wil[du * 3 + c4 - 1];
                a1r = fmaf(w0, vr, a1r); a1r = fmaf(-w1, vi, a1r);
                a1i = fmaf(w1, vr, a1i); a1i = fmaf(w0, vi, a1i);
            }
        }
    }

    if (ch < 128) {
        int pl = (ch < 64) ? 0 : 2;
        int row = ch & 63;
        u16* base = dwp + ((size_t)pl * 64 + row) * SP + p2;
        *(u32*)base          = pack2(a0r, a1r);
        *(u32*)(base + (size_t)64 * SP) = pack2(a0i, a1i);   // imag plane (pl+1)
    } else {
        int e = ch - 128;
        uint2 vv = make_uint2(pack2(a0r, a0i), pack2(a1r, a1i));
        *(uint2*)&vpack[(size_t)e * HWS + (s * R + r64) * 256 + h] = vv;
    }
}

// ---------------- Kernel C: q k^T + fused sumsq via MFMA (no LDS) ----------------
// dwp planes [4][64][SP]; rnsum [2][128][2]; attn [2][2][64][64]
__global__ __launch_bounds__(256) void k_qk(const u16* __restrict__ dwp,
                                            float* __restrict__ rnsum,
                                            float* __restrict__ attn,
                                            int b, int SP) {
    const int chunk = blockIdx.x;        // 0..31
    const int d = blockIdx.y;
    const int Kc = SP >> 5;
    const int kc0 = chunk * Kc;
    const u16* qp = dwp + (size_t)d * 64 * SP;
    const u16* kp = dwp + (size_t)(2 + d) * 64 * SP;

    const int t = threadIdx.x, lane = t & 63, wid = t >> 6;
    const int wy = wid >> 1, wx = wid & 1;
    const int l15 = lane & 15, l4 = lane >> 4;

    f32x4 zz = {0.f, 0.f, 0.f, 0.f};
    f32x4 acc[2][2] = {{zz, zz}, {zz, zz}};
    float sq[2] = {0.f, 0.f}, sk[2] = {0.f, 0.f};

    const int iters = Kc >> 5;
    for (int ks = 0; ks < iters; ++ks) {
        int k0 = kc0 + ks * 32 + 8 * l4;
        bf16x8 aq[2], bk[2];
#pragma unroll
        for (int cf = 0; cf < 2; ++cf)
            aq[cf] = *(const bf16x8*)&qp[(size_t)(32 * wy + 16 * cf + l15) * SP + k0];
#pragma unroll
        for (int ef = 0; ef < 2; ++ef)
            bk[ef] = *(const bf16x8*)&kp[(size_t)(32 * wx + 16 * ef + l15) * SP + k0];

        if (wx == 0)
#pragma unroll
            for (int cf = 0; cf < 2; ++cf)
#pragma unroll
                for (int j = 0; j < 8; ++j) {
                    float f = bf2f((u16)aq[cf][j]);
                    sq[cf] = fmaf(f, f, sq[cf]);
                }
        if (wy == 0)
#pragma unroll
            for (int ef = 0; ef < 2; ++ef)
#pragma unroll
                for (int j = 0; j < 8; ++j) {
                    float f = bf2f((u16)bk[ef][j]);
                    sk[ef] = fmaf(f, f, sk[ef]);
                }

#pragma unroll
        for (int cf = 0; cf < 2; ++cf)
#pragma unroll
            for (int ef = 0; ef < 2; ++ef)
                acc[cf][ef] = __builtin_amdgcn_mfma_f32_16x16x32_bf16(aq[cf], bk[ef], acc[cf][ef], 0, 0, 0);
    }

#pragma unroll
    for (int cf = 0; cf < 2; ++cf)
#pragma unroll
        for (int ef = 0; ef < 2; ++ef)
#pragma unroll
            for (int r = 0; r < 4; ++r) {
                int cq = 32 * wy + 16 * cf + 4 * l4 + r;
                int ce = 32 * wx + 16 * ef + l15;
                atomicAdd(&attn[((b * 2 + d) * 64 + cq) * 64 + ce], acc[cf][ef][r]);
            }

    if (wx == 0)
#pragma unroll
        for (int cf = 0; cf < 2; ++cf) {
            float v = sq[cf];
            v += __shfl_xor(v, 16);
            v += __shfl_xor(v, 32);
            if (lane < 16)
                atomicAdd(&rnsum[((size_t)b * 128 + 32 * wy + 16 * cf + lane) * 2 + d], v);
        }
    if (wy == 0)
#pragma unroll
        for (int ef = 0; ef < 2; ++ef) {
            float v = sk[ef];
            v += __shfl_xor(v, 16);
            v += __shfl_xor(v, 32);
            if (lane < 16)
                atomicAdd(&rnsum[((size_t)b * 128 + 64 + 32 * wx + 16 * ef + lane) * 2 + d], v);
        }
}

// ---------------- Kernel D1: scale + row softmax -> P (grid (2b,2d), 64 thr) ----------------
__global__ __launch_bounds__(64) void k_prob(const float* __restrict__ attn,
                                             const float* __restrict__ rnsum,
                                             float* __restrict__ P) {
    int b = blockIdx.x, d = blockIdx.y;
    int t = threadIdx.x;
    __shared__ float rks[64];
    float sk = rnsum[((size_t)b * 128 + 64 + t) * 2 + d];
    rks[t] = 1.0f / fmaxf(sqrtf(sk), 1e-12f);
    float sq = rnsum[((size_t)b * 128 + t) * 2 + d];
    float rq = 1.0f / fmaxf(sqrtf(sq), 1e-12f);
    __syncthreads();

    const float* arow = attn + ((size_t)(b * 2 + d) * 64 + t) * 64;
    float v[64];
    float m = -1e30f;
#pragma unroll
    for (int e = 0; e < 64; ++e) { v[e] = arow[e] * rq * rks[e]; m = fmaxf(m, v[e]); }
    float ssum = 0.f;
#pragma unroll
    for (int e = 0; e < 64; ++e) { v[e] = __expf(v[e] - m); ssum += v[e]; }
    float r = 1.0f / ssum;
    float* prow = P + ((size_t)(b * 2 + d) * 64 + t) * 64;
#pragma unroll
    for (int e = 0; e < 64; ++e) prow[e] = v[e] * r;
}

// ---------------- Kernel D2: build A_big from P and proj weights ----------------
// grid (16, 2b), 256 thr; each thread one (co,e)
// A_big[b] [128][128] u16: [2co][2e]=M1 [2co][2e+1]=-M2 [2co+1][2e]=M4 [2co+1][2e+1]=M3
__global__ __launch_bounds__(256) void k_M(const float* __restrict__ P,
                                           const float* __restrict__ pwr,
                                           const float* __restrict__ pwi,
                                           u16* __restrict__ Abig) {
    int b = blockIdx.y;
    int pair = blockIdx.x * 256 + threadIdx.x;   // 0..4095
    __shared__ float P0[64][64], P1[64][64];     // 32 KB
    __shared__ float Wr[64][64], Wi2[64][64];    // 32 KB
    for (int i = threadIdx.x; i < 4096; i += 256) {
        P0[i >> 6][i & 63] = P[(size_t)(b * 2 + 0) * 4096 + i];
        P1[i >> 6][i & 63] = P[(size_t)(b * 2 + 1) * 4096 + i];
        Wr[i >> 6][i & 63] = pwr[i];
        Wi2[i >> 6][i & 63] = pwi[i];
    }
    __syncthreads();
    int co = pair >> 6, e = pair & 63;
    float m1 = 0.f, m2 = 0.f, m3 = 0.f, m4 = 0.f;
#pragma unroll 8
    for (int c = 0; c < 64; ++c) {
        float pr = Wr[co][c], pi = Wi2[co][c];
        float a0 = P0[c][e], a1 = P1[c][e];
        m1 = fmaf(pr, a0, m1);
        m2 = fmaf(pi, a1, m2);
        m3 = fmaf(pr, a1, m3);
        m4 = fmaf(pi, a0, m4);
    }
    u16* AB = Abig + (size_t)b * 16384;
    AB[(2 * co) * 128 + 2 * e]         = f2bf(m1);
    AB[(2 * co) * 128 + 2 * e + 1]     = f2bf(-m2);
    AB[(2 * co + 1) * 128 + 2 * e]     = f2bf(m4);
    AB[(2 * co + 1) * 128 + 2 * e + 1] = f2bf(m3);
}

// ---------------- Kernel E: transpose vpack [64][HWS] u32 -> vT [HWS][64] u32 ----------------
__global__ __launch_bounds__(256) void k_vt(const u32* __restrict__ in,
                                            u32* __restrict__ outp) {
    __shared__ u32 tile[64][65];
    int p0 = blockIdx.x << 6;
    int t = threadIdx.x;
    for (int i = t; i < 4096; i += 256) {
        int e = i >> 6, c = i & 63;
        tile[e][c] = in[(size_t)e * HWS + p0 + c];
    }
    __syncthreads();
    for (int i = t; i < 4096; i += 256) {
        int r = i >> 6, e = i & 63;
        outp[(size_t)(p0 + r) * 64 + e] = tile[e][r];
    }
}

// ---------------- Kernel F: out = A_big * vT via MFMA (no LDS) ----------------
// vT as u16 [HWS][128]; A_big[b] [128][128] u16; outb f32 [64][HWS][2]
__global__ __launch_bounds__(256) void k_out(const u16* __restrict__ Abig,
                                             const u16* __restrict__ vT,
                                             float* __restrict__ outb) {
    const int p0 = blockIdx.x << 6;
    const int t = threadIdx.x, lane = t & 63, w = t >> 6;
    const int l15 = lane & 15, l4 = lane >> 4;

    bf16x8 Af[2][4];
#pragma unroll
    for (int cf = 0; cf < 2; ++cf)
#pragma unroll
        for (int ks = 0; ks < 4; ++ks)
            Af[cf][ks] = *(const bf16x8*)&Abig[(size_t)(32 * w + 16 * cf + l15) * 128 + 32 * ks + 8 * l4];

    f32x4 zz = {0.f, 0.f, 0.f, 0.f};
    f32x4 acc[2][4];
#pragma unroll
    for (int cf = 0; cf < 2; ++cf)
#pragma unroll
        for (int nf = 0; nf < 4; ++nf) acc[cf][nf] = zz;

#pragma unroll
    for (int ks = 0; ks < 4; ++ks) {
        bf16x8 Bf[4];
#pragma unroll
        for (int nf = 0; nf < 4; ++nf)
            Bf[nf] = *(const bf16x8*)&vT[(size_t)(p0 + 16 * nf + l15) * 128 + 32 * ks + 8 * l4];
#pragma unroll
        for (int cf = 0; cf < 2; ++cf)
#pragma unroll
            for (int nf = 0; nf < 4; ++nf)
                acc[cf][nf] = __builtin_amdgcn_mfma_f32_16x16x32_bf16(Af[cf][ks], Bf[nf], acc[cf][nf], 0, 0, 0);
    }

    float2* o2 = (float2*)outb;
#pragma unroll
    for (int cf = 0; cf < 2; ++cf)
#pragma unroll
        for (int nf = 0; nf < 4; ++nf) {
            int co = 16 * w + 8 * cf + 2 * l4;
            int p = p0 + 16 * nf + l15;
            o2[(size_t)co * HWS + p]       = make_float2(acc[cf][nf][0], acc[cf][nf][1]);
            o2[(size_t)(co + 1) * HWS + p] = make_float2(acc[cf][nf][2], acc[cf][nf][3]);
        }
}

extern "C" void kernel_launch(void* const* d_in, const int* in_sizes, int n_in,
                              void* d_out, int out_size, void* d_ws, size_t ws_size,
                              hipStream_t stream) {
    const float* x      = (const float*)d_in[0];
    const float* qkv_wr = (const float*)d_in[1];
    const float* qkv_wi = (const float*)d_in[2];
    const float* dw_wr  = (const float*)d_in[3];
    const float* dw_wi  = (const float*)d_in[4];
    const float* p_wr   = (const float*)d_in[5];
    const float* p_wi   = (const float*)d_in[6];
    float* out = (float*)d_out;

    int R;
    if (ws_size >= 104ull * 1000 * 1000)      R = 256;
    else if (ws_size >= 62ull * 1000 * 1000)  R = 128;
    else                                      R = 64;
    const int S = 256 / R;
    const int SP = R << 8;
    int lsh = 13;                    // log2(SP/2)
    if (R == 128) lsh = 14;
    if (R == 256) lsh = 15;

    char* base = (char*)d_ws;
    size_t qs_bytes = (size_t)192 * (R + 2) * 256 * 4;
    size_t dw_bytes = (size_t)4 * 64 * SP * 2;
    size_t vt_bytes = (size_t)HWS * 64 * 4;    // shared: xT planes during strips, vT after
    u32*   qs_u  = (u32*)base;
    u16*   dwp   = (u16*)(base + qs_bytes);
    u32*   vT    = (u32*)(base + qs_bytes + dw_bytes);
    u16*   xTr   = (u16*)vT;
    u16*   xTi   = xTr + (size_t)HWS * 64;
    u16*   wbf   = (u16*)(base + qs_bytes + dw_bytes + vt_bytes);
    u16*   Abig  = (u16*)(base + qs_bytes + dw_bytes + vt_bytes + 73728);
    float* rnsum = (float*)(base + qs_bytes + dw_bytes + vt_bytes + 73728 + 65536);
    float* attn  = rnsum + 512;
    float* Pbuf  = attn + 16384;

    k_wcvt<<<48, 256, 0, stream>>>(qkv_wr, qkv_wi, wbf);
    k_zero<<<66, 256, 0, stream>>>(rnsum, 512 + 16384);

    for (int b = 0; b < 2; ++b) {
        const float* xb = x + (size_t)b * 64 * HWS * 2;
        u32* vpack = (u32*)(out + (size_t)b * 64 * HWS * 2);
        k_xt<<<1024, 256, 0, stream>>>(xb, xTr, xTi);
        for (int s = 0; s < S; ++s) {
            k_qkv<<<dim3(6, R + 2), 256, 0, stream>>>(xTr, xTi, wbf, qs_u, s, R);
            k_dw<<<(192 * SP / 2) / 256, 256, 0, stream>>>(qs_u, dw_wr, dw_wi,
                                                           dwp, vpack, s, R, lsh);
            k_qk<<<dim3(32, 2), 256, 0, stream>>>(dwp, rnsum, attn, b, SP);
        }
    }
    k_prob<<<dim3(2, 2), 64, 0, stream>>>(attn, rnsum, Pbuf);
    k_M<<<dim3(16, 2), 256, 0, stream>>>(Pbuf, p_wr, p_wi, Abig);
    for (int b = 0; b < 2; ++b) {
        u32* vpack = (u32*)(out + (size_t)b * 64 * HWS * 2);
        k_vt<<<1024, 256, 0, stream>>>(vpack, vT);
        k_out<<<1024, 256, 0, stream>>>(Abig + (size_t)b * 16384, (const u16*)vT,
                                        out + (size_t)b * 64 * HWS * 2);
    }
}